// Round 13
// baseline (495.499 us; speedup 1.0000x reference)
//
#include <hip/hip_runtime.h>
#include <hip/hip_bf16.h>

// Mixtral sparse MoE: T=4096 tokens, D=1024, F=3584, E=8, top-2.
// route(+x->bf16 into d_out) -> scan(pad256) -> scatter(tokPos) -> cvt2(w1,w3)
//   -> GEMM1 (256x128, 4 waves of 128x64, ring-3, vmcnt(6), 1-phase, silu*mul -> h)
//   -> cvt(w2, overlays w1b) -> GEMM2 (256x128, splitK=2, ring-3, 1-phase, res stores)
//   -> combine (out = wA*(res0[pA]+res1[pA]) + wB*(res0[pB]+res1[pB]))
// Delta vs r12: merged the two MFMA phases per K-iter (4 BAR + 2 LGKM -> 2 BAR + 1 LGKM).

#define T_TOK 4096
#define DIM   1024
#define FF    3584
#define NE    8
#define CAP   (T_TOK*2 + NE*256)   // 10240 padded pair rows (pad-256)

// ws byte offsets (WS_NEED = 190,988,544 — verified budget)
#define OFF_TOPI   256UL
#define OFF_TOPW   33024UL
#define OFF_ROWTOK 65792UL
#define OFF_TOKPOS 106752UL
#define OFF_W1B    147712UL
#define OFF_W3B    (OFF_W1B + 58720256UL)
#define OFF_W2B    OFF_W1B                      // overlays dead w1b after GEMM1
#define OFF_RES    OFF_W3B                      // overlays dead w3b after GEMM1 (42MB<56MB)
#define OFF_H      (OFF_W1B + 117440512UL)
#define WS_NEED    (OFF_H + 73400320UL)

using f32x4 = __attribute__((ext_vector_type(4))) float;
using s16x8 = __attribute__((ext_vector_type(8))) short;

__device__ __forceinline__ ushort f2b(float f) {
    __hip_bfloat16 b = __float2bfloat16(f);   // RNE
    ushort u; __builtin_memcpy(&u, &b, 2); return u;
}
__device__ __forceinline__ float blo(uint u){ u <<= 16; float f; __builtin_memcpy(&f,&u,4); return f; }
__device__ __forceinline__ float bhi(uint u){ u &= 0xFFFF0000u; float f; __builtin_memcpy(&f,&u,4); return f; }
__device__ __forceinline__ void gl_lds16(const ushort* g, ushort* l) {
    __builtin_amdgcn_global_load_lds(
        (const __attribute__((address_space(1))) void*)g,
        (__attribute__((address_space(3))) void*)l, 16, 0, 0);
}
__device__ __forceinline__ uint4 pack8(float4 v0, float4 v1) {
    uint4 o;
    o.x = f2b(v0.x) | ((uint)f2b(v0.y) << 16);
    o.y = f2b(v0.z) | ((uint)f2b(v0.w) << 16);
    o.z = f2b(v1.x) | ((uint)f2b(v1.y) << 16);
    o.w = f2b(v1.z) | ((uint)f2b(v1.w) << 16);
    return o;
}

#define LGKM0 do { asm volatile("s_waitcnt lgkmcnt(0)" ::: "memory"); \
                   __builtin_amdgcn_sched_barrier(0); } while (0)
#define VMC(n) asm volatile("s_waitcnt vmcnt(" #n ")" ::: "memory")
#define BAR()  __builtin_amdgcn_s_barrier()

// ---------------- routing: one wave per token; also emits xb (bf16) ---------
__global__ __launch_bounds__(256)
void k_route(const float* __restrict__ x, const float* __restrict__ gw,
             int* __restrict__ topi, float* __restrict__ topw,
             int* __restrict__ counts, ushort* __restrict__ xb)
{
    __shared__ float gws[NE*DIM];
    const int tid = threadIdx.x;
    for (int i = tid; i < NE*DIM/4; i += 256)
        ((float4*)gws)[i] = ((const float4*)gw)[i];
    __syncthreads();

    const int lane = tid & 63, wid = tid >> 6;
    const int t = blockIdx.x*4 + wid;

    float4 xr[4];
    const float4* xrow = (const float4*)(x + (size_t)t*DIM) + lane*4;
    #pragma unroll
    for (int i = 0; i < 4; ++i) xr[i] = xrow[i];

    // emit bf16 copy of x (lane covers elements [lane*16, lane*16+16))
    uint4* xbd = (uint4*)(xb + (size_t)t*DIM);
    xbd[lane*2]   = pack8(xr[0], xr[1]);
    xbd[lane*2+1] = pack8(xr[2], xr[3]);

    float lg[NE];
    #pragma unroll
    for (int e = 0; e < NE; ++e) {
        const float4* g4 = (const float4*)(gws + e*DIM) + lane*4;
        float s = 0.f;
        #pragma unroll
        for (int i = 0; i < 4; ++i) {
            float4 g = g4[i];
            s += xr[i].x*g.x + xr[i].y*g.y + xr[i].z*g.z + xr[i].w*g.w;
        }
        #pragma unroll
        for (int off = 32; off; off >>= 1) s += __shfl_xor(s, off);
        lg[e] = s;
    }
    if (lane == 0) {
        float b1 = -1e30f, b2 = -1e30f; int i1 = 0, i2 = 0;
        #pragma unroll
        for (int e = 0; e < NE; ++e) {
            float v = lg[e];
            if (v > b1)      { b2 = b1; i2 = i1; b1 = v; i1 = e; }
            else if (v > b2) { b2 = v; i2 = e; }
        }
        float p2 = __expf(b2 - b1);     // softmax denom cancels in top-k renorm
        float inv = 1.f / (1.f + p2);
        topi[2*t]   = i1; topi[2*t+1] = i2;
        topw[2*t]   = inv; topw[2*t+1] = p2*inv;
        atomicAdd(&counts[i1], 1); atomicAdd(&counts[i2], 1);
    }
}

// ---------------- scan: per-expert offsets padded to 256 ----------------
__global__ void k_scan(const int* __restrict__ counts, int* __restrict__ offs,
                       int* __restrict__ rowTok)
{
    if (threadIdx.x == 0) {
        int acc = 0; offs[0] = 0;
        for (int e = 0; e < NE; ++e) {
            int p = (counts[e] + 255) & ~255;
            acc += p; offs[e+1] = acc;
        }
    }
    for (int i = threadIdx.x; i < CAP; i += blockDim.x) rowTok[i] = -1;
}

// ---------------- scatter tokens into per-expert row lists ----------------
__global__ __launch_bounds__(256)
void k_scatter(const int* __restrict__ topi,
               const int* __restrict__ offs, int* __restrict__ cursor,
               int* __restrict__ rowTok, int* __restrict__ tokPos)
{
    int t = blockIdx.x*256 + threadIdx.x;
    #pragma unroll
    for (int j = 0; j < 2; ++j) {
        int e = topi[2*t + j];
        int pos = offs[e] + atomicAdd(&cursor[e], 1);
        rowTok[pos] = t;
        tokPos[2*t + j] = pos;
    }
}

// ---------------- fp32 -> bf16 straight streaming convert (w2) --------------
__global__ __launch_bounds__(256)
void k_cvt(const float* __restrict__ src, ushort* __restrict__ dst)
{
    size_t i = (size_t)blockIdx.x*256 + threadIdx.x;
    float4 v0 = ((const float4*)src)[2*i], v1 = ((const float4*)src)[2*i+1];
    ((uint4*)dst)[i] = pack8(v0, v1);
}

// ---------------- merged convert: w1 -> w1b, w3 -> w3b ----------------
#define CVT_HALF ((NE*FF*DIM/8)/256)   // 28672 blocks per tensor
__global__ __launch_bounds__(256)
void k_cvt2(const float* __restrict__ w1, const float* __restrict__ w3,
            ushort* __restrict__ w1b, ushort* __restrict__ w3b)
{
    int b = blockIdx.x;
    const float* src; ushort* dst;
    if (b < CVT_HALF) { src = w1; dst = w1b; }
    else              { src = w3; dst = w3b; b -= CVT_HALF; }
    size_t i = (size_t)b*256 + threadIdx.x;
    float4 v0 = ((const float4*)src)[2*i], v1 = ((const float4*)src)[2*i+1];
    ((uint4*)dst)[i] = pack8(v0, v1);
}

// ---------------- GEMM1: 256 rows x 128 stacked-cols, BK=32, 1-phase --------
// 4 waves of 128x64, ring-3 LDS (72 KB, 2 blocks/CU), counted vmcnt(6).
#define G1_SLOT 12288   // ushorts per slot: A 8192 + B 4096
__global__ __launch_bounds__(256, 2)
void k_gemm1(const ushort* __restrict__ xb,
             const ushort* __restrict__ w1b, const ushort* __restrict__ w3b,
             const int* __restrict__ offs, const int* __restrict__ rowTok,
             ushort* __restrict__ hout)
{
    __shared__ __align__(16) ushort L[3*G1_SLOT];   // 72 KB
    const int sb = blockIdx.x;                 // f-block 0..55
    const int rowStart = blockIdx.y * 256;
    if (rowStart >= offs[8]) return;
    int e = 0;
    #pragma unroll
    for (int k = 1; k < NE; ++k) if (rowStart >= offs[k]) e = k;

    const int tid = threadIdx.x, lane = tid & 63, wid = tid >> 6;
    const int wr = wid >> 1, wc = wid & 1;     // wave tile 128x64
    const int lo = lane & 15, hi = lane >> 4;

    const int srow = lane >> 2;
    const int sch  = (lane & 3) ^ ((lane >> 3) & 3);
    const ushort* aS[4];
    #pragma unroll
    for (int j = 0; j < 4; ++j) {
        int tk = rowTok[rowStart + j*64 + wid*16 + srow]; if (tk < 0) tk = 0;
        aS[j] = xb + (size_t)tk*DIM + sch*8;
    }
    const ushort* bS[2];
    bS[0] = w1b + ((size_t)e*FF + sb*64 + wid*16 + srow)*DIM + sch*8;
    bS[1] = w3b + ((size_t)e*FF + sb*64 + wid*16 + srow)*DIM + sch*8;
    ushort* const dA = L + wid*512;            // + slot*G1_SLOT + j*2048
    ushort* const dB = L + 8192 + wid*512;     // + slot*G1_SLOT + j*2048

    const int sig = (lo >> 1) & 3;
    const int roff = ((hi ^ sig) * 8);
    int rdA[8], rdB[4];
    #pragma unroll
    for (int m = 0; m < 8; ++m) rdA[m] = (wr*128 + m*16 + lo)*32 + roff;
    #pragma unroll
    for (int n = 0; n < 2; ++n) {
        rdB[n]   = 8192 + (wc*32 + n*16 + lo)*32 + roff;
        rdB[n+2] = 8192 + (64 + wc*32 + n*16 + lo)*32 + roff;
    }

    f32x4 acc[8][4];
    #pragma unroll
    for (int m = 0; m < 8; ++m)
        #pragma unroll
        for (int n = 0; n < 4; ++n) acc[m][n] = (f32x4)(0.f);

    #pragma unroll
    for (int t0 = 0; t0 < 2; ++t0) {
        #pragma unroll
        for (int j = 0; j < 4; ++j) gl_lds16(aS[j] + t0*32, dA + t0*G1_SLOT + j*2048);
        #pragma unroll
        for (int j = 0; j < 2; ++j) gl_lds16(bS[j] + t0*32, dB + t0*G1_SLOT + j*2048);
    }
    VMC(6);
    BAR();

    const int NK = DIM/32;   // 32
    int cur = 0, nxt = 2;
    for (int t = 0; t < NK; ++t) {
        const ushort* Lb = L + cur*G1_SLOT;
        const bool pf = (t + 2 < NK);
        s16x8 a[8], b[4];
        #pragma unroll
        for (int n = 0; n < 4; ++n) b[n] = *(const s16x8*)(Lb + rdB[n]);
        #pragma unroll
        for (int m = 0; m < 8; ++m) a[m] = *(const s16x8*)(Lb + rdA[m]);
        if (pf) {
            #pragma unroll
            for (int j = 0; j < 4; ++j)
                gl_lds16(aS[j] + (t+2)*32, dA + nxt*G1_SLOT + j*2048);
            gl_lds16(bS[0] + (t+2)*32, dB + nxt*G1_SLOT);
            gl_lds16(bS[1] + (t+2)*32, dB + nxt*G1_SLOT + 2048);
        }
        BAR();
        LGKM0;
        __builtin_amdgcn_s_setprio(1);
        #pragma unroll
        for (int m = 0; m < 8; ++m)
            #pragma unroll
            for (int n = 0; n < 4; ++n)
                acc[m][n] = __builtin_amdgcn_mfma_f32_16x16x32_bf16(a[m], b[n], acc[m][n], 0, 0, 0);
        __builtin_amdgcn_s_setprio(0);
        if (t < NK-2) { VMC(6); } else { VMC(0); }
        BAR();
        cur = (cur == 2) ? 0 : cur + 1;
        nxt = (nxt == 2) ? 0 : nxt + 1;
    }

    // epilogue: silu(acc[m][p]) * acc[m][p+2] -> h
    #pragma unroll
    for (int m = 0; m < 8; ++m)
        #pragma unroll
        for (int p = 0; p < 2; ++p) {
            f32x4 v1 = acc[m][p], v3 = acc[m][p+2];
            int f = sb*64 + wc*32 + p*16 + lo;
            #pragma unroll
            for (int j = 0; j < 4; ++j) {
                int row = rowStart + wr*128 + m*16 + hi*4 + j;
                float s = v1[j];
                float val = (s / (1.f + __expf(-s))) * v3[j];
                hout[(size_t)row*FF + f] = f2b(val);
            }
        }
}

// ---------------- GEMM2: 256 rows x 128 d-cols, BK=32, splitK=2, 1-phase ----
__global__ __launch_bounds__(256, 2)
void k_gemm2(const ushort* __restrict__ h, const ushort* __restrict__ w2b,
             const int* __restrict__ offs, ushort* __restrict__ res)
{
    __shared__ __align__(16) ushort L[3*G1_SLOT];   // 72 KB
    const int dc = blockIdx.x * 128;
    const int rowStart = blockIdx.y * 256;
    if (rowStart >= offs[8]) return;
    int e = 0;
    #pragma unroll
    for (int k = 1; k < NE; ++k) if (rowStart >= offs[k]) e = k;
    const int kbase = blockIdx.z * (FF/2);     // 0 or 1792

    const int tid = threadIdx.x, lane = tid & 63, wid = tid >> 6;
    const int wr = wid >> 1, wc = wid & 1;     // wave tile 128x64
    const int lo = lane & 15, hi = lane >> 4;

    const int srow = lane >> 2;
    const int sch  = (lane & 3) ^ ((lane >> 3) & 3);
    const ushort* aS[4];
    #pragma unroll
    for (int j = 0; j < 4; ++j)
        aS[j] = h + (size_t)(rowStart + j*64 + wid*16 + srow)*FF + kbase + sch*8;
    const ushort* bS[2];
    #pragma unroll
    for (int j = 0; j < 2; ++j)
        bS[j] = w2b + ((size_t)e*DIM + dc + j*64 + wid*16 + srow)*FF + kbase + sch*8;
    ushort* const dA = L + wid*512;
    ushort* const dB = L + 8192 + wid*512;

    const int sig = (lo >> 1) & 3;
    const int roff = ((hi ^ sig) * 8);
    int rdA[8], rdB[4];
    #pragma unroll
    for (int m = 0; m < 8; ++m) rdA[m] = (wr*128 + m*16 + lo)*32 + roff;
    #pragma unroll
    for (int n = 0; n < 4; ++n) rdB[n] = 8192 + (wc*64 + n*16 + lo)*32 + roff;

    f32x4 acc[8][4];
    #pragma unroll
    for (int m = 0; m < 8; ++m)
        #pragma unroll
        for (int n = 0; n < 4; ++n) acc[m][n] = (f32x4)(0.f);

    #pragma unroll
    for (int t0 = 0; t0 < 2; ++t0) {
        #pragma unroll
        for (int j = 0; j < 4; ++j) gl_lds16(aS[j] + t0*32, dA + t0*G1_SLOT + j*2048);
        #pragma unroll
        for (int j = 0; j < 2; ++j) gl_lds16(bS[j] + t0*32, dB + t0*G1_SLOT + j*2048);
    }
    VMC(6);
    BAR();

    const int NK = (FF/2)/32;   // 56
    int cur = 0, nxt = 2;
    for (int t = 0; t < NK; ++t) {
        const ushort* Lb = L + cur*G1_SLOT;
        const bool pf = (t + 2 < NK);
        s16x8 a[8], b[4];
        #pragma unroll
        for (int n = 0; n < 4; ++n) b[n] = *(const s16x8*)(Lb + rdB[n]);
        #pragma unroll
        for (int m = 0; m < 8; ++m) a[m] = *(const s16x8*)(Lb + rdA[m]);
        if (pf) {
            #pragma unroll
            for (int j = 0; j < 4; ++j)
                gl_lds16(aS[j] + (t+2)*32, dA + nxt*G1_SLOT + j*2048);
            gl_lds16(bS[0] + (t+2)*32, dB + nxt*G1_SLOT);
            gl_lds16(bS[1] + (t+2)*32, dB + nxt*G1_SLOT + 2048);
        }
        BAR();
        LGKM0;
        __builtin_amdgcn_s_setprio(1);
        #pragma unroll
        for (int m = 0; m < 8; ++m)
            #pragma unroll
            for (int n = 0; n < 4; ++n)
                acc[m][n] = __builtin_amdgcn_mfma_f32_16x16x32_bf16(a[m], b[n], acc[m][n], 0, 0, 0);
        __builtin_amdgcn_s_setprio(0);
        if (t < NK-2) { VMC(6); } else { VMC(0); }
        BAR();
        cur = (cur == 2) ? 0 : cur + 1;
        nxt = (nxt == 2) ? 0 : nxt + 1;
    }

    // epilogue: plain bf16 stores to res[z][prow][d] — no atomics, deterministic
    ushort* rz = res + (size_t)blockIdx.z * CAP * DIM;
    #pragma unroll
    for (int m = 0; m < 8; ++m)
        #pragma unroll
        for (int j = 0; j < 4; ++j) {
            int prow = rowStart + wr*128 + m*16 + hi*4 + j;
            #pragma unroll
            for (int n = 0; n < 4; ++n) {
                int d = dc + wc*64 + n*16 + lo;
                rz[(size_t)prow*DIM + d] = f2b(acc[m][n][j]);
            }
        }
}

// ---------------- combine: out[t] = wA*(res0+res1)[pA] + wB*(res0+res1)[pB] --
__global__ __launch_bounds__(256)
void k_combine(const ushort* __restrict__ res, const int* __restrict__ tokPos,
               const float* __restrict__ topw, float* __restrict__ out)
{
    int i = blockIdx.x*256 + threadIdx.x;    // 8-elem group
    int t = i >> 7;                           // D/8 = 128 groups per token
    int g = i & 127;
    int pA = tokPos[2*t], pB = tokPos[2*t+1];
    float wA = topw[2*t], wB = topw[2*t+1];
    const ushort* res1 = res + (size_t)CAP * DIM;
    uint4 a0 = *(const uint4*)(res  + (size_t)pA*DIM + g*8);
    uint4 a1 = *(const uint4*)(res1 + (size_t)pA*DIM + g*8);
    uint4 b0 = *(const uint4*)(res  + (size_t)pB*DIM + g*8);
    uint4 b1 = *(const uint4*)(res1 + (size_t)pB*DIM + g*8);
    float4 o0, o1;
    o0.x = wA*(blo(a0.x)+blo(a1.x)) + wB*(blo(b0.x)+blo(b1.x));
    o0.y = wA*(bhi(a0.x)+bhi(a1.x)) + wB*(bhi(b0.x)+bhi(b1.x));
    o0.z = wA*(blo(a0.y)+blo(a1.y)) + wB*(blo(b0.y)+blo(b1.y));
    o0.w = wA*(bhi(a0.y)+bhi(a1.y)) + wB*(bhi(b0.y)+bhi(b1.y));
    o1.x = wA*(blo(a0.z)+blo(a1.z)) + wB*(blo(b0.z)+blo(b1.z));
    o1.y = wA*(bhi(a0.z)+bhi(a1.z)) + wB*(bhi(b0.z)+bhi(b1.z));
    o1.z = wA*(blo(a0.w)+blo(a1.w)) + wB*(blo(b0.w)+blo(b1.w));
    o1.w = wA*(bhi(a0.w)+bhi(a1.w)) + wB*(bhi(b0.w)+bhi(b1.w));
    float4* dst = (float4*)(out + (size_t)t*DIM + g*8);
    dst[0] = o0; dst[1] = o1;
}

// ---------------- launch ----------------
extern "C" void kernel_launch(void* const* d_in, const int* in_sizes, int n_in,
                              void* d_out, int out_size, void* d_ws, size_t ws_size,
                              hipStream_t stream)
{
    const float* x  = (const float*)d_in[0];
    const float* gw = (const float*)d_in[1];
    const float* w1 = (const float*)d_in[2];
    const float* w3 = (const float*)d_in[3];
    const float* w2 = (const float*)d_in[4];
    float* out = (float*)d_out;
    char* ws = (char*)d_ws;
    if (ws_size < WS_NEED) return;   // fail loudly

    int*    counts = (int*)ws;
    int*    cursor = counts + 8;
    int*    offs   = counts + 16;
    int*    topi   = (int*)  (ws + OFF_TOPI);
    float*  topw   = (float*)(ws + OFF_TOPW);
    int*    rowTok = (int*)  (ws + OFF_ROWTOK);
    int*    tokPos = (int*)  (ws + OFF_TOKPOS);
    ushort* w1b    = (ushort*)(ws + OFF_W1B);
    ushort* w3b    = (ushort*)(ws + OFF_W3B);
    ushort* w2b    = (ushort*)(ws + OFF_W2B);
    ushort* res    = (ushort*)(ws + OFF_RES);
    ushort* h      = (ushort*)(ws + OFF_H);
    ushort* xb     = (ushort*)d_out;          // xb lives in d_out until combine

    hipMemsetAsync(ws, 0, 256, stream);   // counts + cursor

    k_route  <<<T_TOK/4, 256, 0, stream>>>(x, gw, topi, topw, counts, xb);
    k_scan   <<<1, 256, 0, stream>>>(counts, offs, rowTok);
    k_scatter<<<T_TOK/256, 256, 0, stream>>>(topi, offs, cursor, rowTok, tokPos);
    k_cvt2   <<<2*CVT_HALF, 256, 0, stream>>>(w1, w3, w1b, w3b);
    k_gemm1  <<<dim3(56, CAP/256), 256, 0, stream>>>(xb, w1b, w3b, offs, rowTok, h);
    k_cvt    <<<(NE*DIM*FF/8)/256, 256, 0, stream>>>(w2, w2b);   // overlays w1b
    k_gemm2  <<<dim3(8, CAP/256, 2), 256, 0, stream>>>(h, w2b, offs, res);
    k_combine<<<(T_TOK*DIM/8)/256, 256, 0, stream>>>(res, tokPos, topw, out);
}

// Round 14
// 494.044 us; speedup vs baseline: 1.0029x; 1.0029x over previous
//
#include <hip/hip_runtime.h>
#include <hip/hip_bf16.h>

// Mixtral sparse MoE: T=4096 tokens, D=1024, F=3584, E=8, top-2.
// route(+x->bf16 into d_out) -> scan(pad256) -> scatter(tokPos) -> cvt2(w1,w3)
//   -> GEMM1 (256x128, 4 waves of 128x64, ring-3, vmcnt(6), 1-phase, silu*mul -> h)
//   -> cvt(w2, overlays w1b) -> GEMM2 (256x128, splitK=2, ring-3, 1-phase, res stores)
//   -> combine (out = wA*(res0[pA]+res1[pA]) + wB*(res0[pB]+res1[pB]))
// Delta vs r13: removed the forced lgkmcnt(0)+sched_barrier(0) drain before the MFMA
// cluster — let hipcc emit its own fine-grained lgkm waits (m97/m141 lessons).

#define T_TOK 4096
#define DIM   1024
#define FF    3584
#define NE    8
#define CAP   (T_TOK*2 + NE*256)   // 10240 padded pair rows (pad-256)

// ws byte offsets (WS_NEED = 190,988,544 — verified budget)
#define OFF_TOPI   256UL
#define OFF_TOPW   33024UL
#define OFF_ROWTOK 65792UL
#define OFF_TOKPOS 106752UL
#define OFF_W1B    147712UL
#define OFF_W3B    (OFF_W1B + 58720256UL)
#define OFF_W2B    OFF_W1B                      // overlays dead w1b after GEMM1
#define OFF_RES    OFF_W3B                      // overlays dead w3b after GEMM1 (42MB<56MB)
#define OFF_H      (OFF_W1B + 117440512UL)
#define WS_NEED    (OFF_H + 73400320UL)

using f32x4 = __attribute__((ext_vector_type(4))) float;
using s16x8 = __attribute__((ext_vector_type(8))) short;

__device__ __forceinline__ ushort f2b(float f) {
    __hip_bfloat16 b = __float2bfloat16(f);   // RNE
    ushort u; __builtin_memcpy(&u, &b, 2); return u;
}
__device__ __forceinline__ float blo(uint u){ u <<= 16; float f; __builtin_memcpy(&f,&u,4); return f; }
__device__ __forceinline__ float bhi(uint u){ u &= 0xFFFF0000u; float f; __builtin_memcpy(&f,&u,4); return f; }
__device__ __forceinline__ void gl_lds16(const ushort* g, ushort* l) {
    __builtin_amdgcn_global_load_lds(
        (const __attribute__((address_space(1))) void*)g,
        (__attribute__((address_space(3))) void*)l, 16, 0, 0);
}
__device__ __forceinline__ uint4 pack8(float4 v0, float4 v1) {
    uint4 o;
    o.x = f2b(v0.x) | ((uint)f2b(v0.y) << 16);
    o.y = f2b(v0.z) | ((uint)f2b(v0.w) << 16);
    o.z = f2b(v1.x) | ((uint)f2b(v1.y) << 16);
    o.w = f2b(v1.z) | ((uint)f2b(v1.w) << 16);
    return o;
}

#define VMC(n) asm volatile("s_waitcnt vmcnt(" #n ")" ::: "memory")
#define BAR()  __builtin_amdgcn_s_barrier()

// ---------------- routing: one wave per token; also emits xb (bf16) ---------
__global__ __launch_bounds__(256)
void k_route(const float* __restrict__ x, const float* __restrict__ gw,
             int* __restrict__ topi, float* __restrict__ topw,
             int* __restrict__ counts, ushort* __restrict__ xb)
{
    __shared__ float gws[NE*DIM];
    const int tid = threadIdx.x;
    for (int i = tid; i < NE*DIM/4; i += 256)
        ((float4*)gws)[i] = ((const float4*)gw)[i];
    __syncthreads();

    const int lane = tid & 63, wid = tid >> 6;
    const int t = blockIdx.x*4 + wid;

    float4 xr[4];
    const float4* xrow = (const float4*)(x + (size_t)t*DIM) + lane*4;
    #pragma unroll
    for (int i = 0; i < 4; ++i) xr[i] = xrow[i];

    // emit bf16 copy of x (lane covers elements [lane*16, lane*16+16))
    uint4* xbd = (uint4*)(xb + (size_t)t*DIM);
    xbd[lane*2]   = pack8(xr[0], xr[1]);
    xbd[lane*2+1] = pack8(xr[2], xr[3]);

    float lg[NE];
    #pragma unroll
    for (int e = 0; e < NE; ++e) {
        const float4* g4 = (const float4*)(gws + e*DIM) + lane*4;
        float s = 0.f;
        #pragma unroll
        for (int i = 0; i < 4; ++i) {
            float4 g = g4[i];
            s += xr[i].x*g.x + xr[i].y*g.y + xr[i].z*g.z + xr[i].w*g.w;
        }
        #pragma unroll
        for (int off = 32; off; off >>= 1) s += __shfl_xor(s, off);
        lg[e] = s;
    }
    if (lane == 0) {
        float b1 = -1e30f, b2 = -1e30f; int i1 = 0, i2 = 0;
        #pragma unroll
        for (int e = 0; e < NE; ++e) {
            float v = lg[e];
            if (v > b1)      { b2 = b1; i2 = i1; b1 = v; i1 = e; }
            else if (v > b2) { b2 = v; i2 = e; }
        }
        float p2 = __expf(b2 - b1);     // softmax denom cancels in top-k renorm
        float inv = 1.f / (1.f + p2);
        topi[2*t]   = i1; topi[2*t+1] = i2;
        topw[2*t]   = inv; topw[2*t+1] = p2*inv;
        atomicAdd(&counts[i1], 1); atomicAdd(&counts[i2], 1);
    }
}

// ---------------- scan: per-expert offsets padded to 256 ----------------
__global__ void k_scan(const int* __restrict__ counts, int* __restrict__ offs,
                       int* __restrict__ rowTok)
{
    if (threadIdx.x == 0) {
        int acc = 0; offs[0] = 0;
        for (int e = 0; e < NE; ++e) {
            int p = (counts[e] + 255) & ~255;
            acc += p; offs[e+1] = acc;
        }
    }
    for (int i = threadIdx.x; i < CAP; i += blockDim.x) rowTok[i] = -1;
}

// ---------------- scatter tokens into per-expert row lists ----------------
__global__ __launch_bounds__(256)
void k_scatter(const int* __restrict__ topi,
               const int* __restrict__ offs, int* __restrict__ cursor,
               int* __restrict__ rowTok, int* __restrict__ tokPos)
{
    int t = blockIdx.x*256 + threadIdx.x;
    #pragma unroll
    for (int j = 0; j < 2; ++j) {
        int e = topi[2*t + j];
        int pos = offs[e] + atomicAdd(&cursor[e], 1);
        rowTok[pos] = t;
        tokPos[2*t + j] = pos;
    }
}

// ---------------- fp32 -> bf16 straight streaming convert (w2) --------------
__global__ __launch_bounds__(256)
void k_cvt(const float* __restrict__ src, ushort* __restrict__ dst)
{
    size_t i = (size_t)blockIdx.x*256 + threadIdx.x;
    float4 v0 = ((const float4*)src)[2*i], v1 = ((const float4*)src)[2*i+1];
    ((uint4*)dst)[i] = pack8(v0, v1);
}

// ---------------- merged convert: w1 -> w1b, w3 -> w3b ----------------
#define CVT_HALF ((NE*FF*DIM/8)/256)   // 28672 blocks per tensor
__global__ __launch_bounds__(256)
void k_cvt2(const float* __restrict__ w1, const float* __restrict__ w3,
            ushort* __restrict__ w1b, ushort* __restrict__ w3b)
{
    int b = blockIdx.x;
    const float* src; ushort* dst;
    if (b < CVT_HALF) { src = w1; dst = w1b; }
    else              { src = w3; dst = w3b; b -= CVT_HALF; }
    size_t i = (size_t)b*256 + threadIdx.x;
    float4 v0 = ((const float4*)src)[2*i], v1 = ((const float4*)src)[2*i+1];
    ((uint4*)dst)[i] = pack8(v0, v1);
}

// ---------------- GEMM1: 256 rows x 128 stacked-cols, BK=32, 1-phase --------
// 4 waves of 128x64, ring-3 LDS (72 KB, 2 blocks/CU), counted vmcnt(6).
#define G1_SLOT 12288   // ushorts per slot: A 8192 + B 4096
__global__ __launch_bounds__(256, 2)
void k_gemm1(const ushort* __restrict__ xb,
             const ushort* __restrict__ w1b, const ushort* __restrict__ w3b,
             const int* __restrict__ offs, const int* __restrict__ rowTok,
             ushort* __restrict__ hout)
{
    __shared__ __align__(16) ushort L[3*G1_SLOT];   // 72 KB
    const int sb = blockIdx.x;                 // f-block 0..55
    const int rowStart = blockIdx.y * 256;
    if (rowStart >= offs[8]) return;
    int e = 0;
    #pragma unroll
    for (int k = 1; k < NE; ++k) if (rowStart >= offs[k]) e = k;

    const int tid = threadIdx.x, lane = tid & 63, wid = tid >> 6;
    const int wr = wid >> 1, wc = wid & 1;     // wave tile 128x64
    const int lo = lane & 15, hi = lane >> 4;

    const int srow = lane >> 2;
    const int sch  = (lane & 3) ^ ((lane >> 3) & 3);
    const ushort* aS[4];
    #pragma unroll
    for (int j = 0; j < 4; ++j) {
        int tk = rowTok[rowStart + j*64 + wid*16 + srow]; if (tk < 0) tk = 0;
        aS[j] = xb + (size_t)tk*DIM + sch*8;
    }
    const ushort* bS[2];
    bS[0] = w1b + ((size_t)e*FF + sb*64 + wid*16 + srow)*DIM + sch*8;
    bS[1] = w3b + ((size_t)e*FF + sb*64 + wid*16 + srow)*DIM + sch*8;
    ushort* const dA = L + wid*512;            // + slot*G1_SLOT + j*2048
    ushort* const dB = L + 8192 + wid*512;     // + slot*G1_SLOT + j*2048

    const int sig = (lo >> 1) & 3;
    const int roff = ((hi ^ sig) * 8);
    int rdA[8], rdB[4];
    #pragma unroll
    for (int m = 0; m < 8; ++m) rdA[m] = (wr*128 + m*16 + lo)*32 + roff;
    #pragma unroll
    for (int n = 0; n < 2; ++n) {
        rdB[n]   = 8192 + (wc*32 + n*16 + lo)*32 + roff;
        rdB[n+2] = 8192 + (64 + wc*32 + n*16 + lo)*32 + roff;
    }

    f32x4 acc[8][4];
    #pragma unroll
    for (int m = 0; m < 8; ++m)
        #pragma unroll
        for (int n = 0; n < 4; ++n) acc[m][n] = (f32x4)(0.f);

    #pragma unroll
    for (int t0 = 0; t0 < 2; ++t0) {
        #pragma unroll
        for (int j = 0; j < 4; ++j) gl_lds16(aS[j] + t0*32, dA + t0*G1_SLOT + j*2048);
        #pragma unroll
        for (int j = 0; j < 2; ++j) gl_lds16(bS[j] + t0*32, dB + t0*G1_SLOT + j*2048);
    }
    VMC(6);
    BAR();

    const int NK = DIM/32;   // 32
    int cur = 0, nxt = 2;
    for (int t = 0; t < NK; ++t) {
        const ushort* Lb = L + cur*G1_SLOT;
        const bool pf = (t + 2 < NK);
        s16x8 a[8], b[4];
        #pragma unroll
        for (int n = 0; n < 4; ++n) b[n] = *(const s16x8*)(Lb + rdB[n]);
        #pragma unroll
        for (int m = 0; m < 8; ++m) a[m] = *(const s16x8*)(Lb + rdA[m]);
        if (pf) {
            #pragma unroll
            for (int j = 0; j < 4; ++j)
                gl_lds16(aS[j] + (t+2)*32, dA + nxt*G1_SLOT + j*2048);
            gl_lds16(bS[0] + (t+2)*32, dB + nxt*G1_SLOT);
            gl_lds16(bS[1] + (t+2)*32, dB + nxt*G1_SLOT + 2048);
        }
        BAR();
        __builtin_amdgcn_s_setprio(1);
        #pragma unroll
        for (int m = 0; m < 8; ++m)
            #pragma unroll
            for (int n = 0; n < 4; ++n)
                acc[m][n] = __builtin_amdgcn_mfma_f32_16x16x32_bf16(a[m], b[n], acc[m][n], 0, 0, 0);
        __builtin_amdgcn_s_setprio(0);
        if (t < NK-2) { VMC(6); } else { VMC(0); }
        BAR();
        cur = (cur == 2) ? 0 : cur + 1;
        nxt = (nxt == 2) ? 0 : nxt + 1;
    }

    // epilogue: silu(acc[m][p]) * acc[m][p+2] -> h
    #pragma unroll
    for (int m = 0; m < 8; ++m)
        #pragma unroll
        for (int p = 0; p < 2; ++p) {
            f32x4 v1 = acc[m][p], v3 = acc[m][p+2];
            int f = sb*64 + wc*32 + p*16 + lo;
            #pragma unroll
            for (int j = 0; j < 4; ++j) {
                int row = rowStart + wr*128 + m*16 + hi*4 + j;
                float s = v1[j];
                float val = (s / (1.f + __expf(-s))) * v3[j];
                hout[(size_t)row*FF + f] = f2b(val);
            }
        }
}

// ---------------- GEMM2: 256 rows x 128 d-cols, BK=32, splitK=2, 1-phase ----
__global__ __launch_bounds__(256, 2)
void k_gemm2(const ushort* __restrict__ h, const ushort* __restrict__ w2b,
             const int* __restrict__ offs, ushort* __restrict__ res)
{
    __shared__ __align__(16) ushort L[3*G1_SLOT];   // 72 KB
    const int dc = blockIdx.x * 128;
    const int rowStart = blockIdx.y * 256;
    if (rowStart >= offs[8]) return;
    int e = 0;
    #pragma unroll
    for (int k = 1; k < NE; ++k) if (rowStart >= offs[k]) e = k;
    const int kbase = blockIdx.z * (FF/2);     // 0 or 1792

    const int tid = threadIdx.x, lane = tid & 63, wid = tid >> 6;
    const int wr = wid >> 1, wc = wid & 1;     // wave tile 128x64
    const int lo = lane & 15, hi = lane >> 4;

    const int srow = lane >> 2;
    const int sch  = (lane & 3) ^ ((lane >> 3) & 3);
    const ushort* aS[4];
    #pragma unroll
    for (int j = 0; j < 4; ++j)
        aS[j] = h + (size_t)(rowStart + j*64 + wid*16 + srow)*FF + kbase + sch*8;
    const ushort* bS[2];
    #pragma unroll
    for (int j = 0; j < 2; ++j)
        bS[j] = w2b + ((size_t)e*DIM + dc + j*64 + wid*16 + srow)*FF + kbase + sch*8;
    ushort* const dA = L + wid*512;
    ushort* const dB = L + 8192 + wid*512;

    const int sig = (lo >> 1) & 3;
    const int roff = ((hi ^ sig) * 8);
    int rdA[8], rdB[4];
    #pragma unroll
    for (int m = 0; m < 8; ++m) rdA[m] = (wr*128 + m*16 + lo)*32 + roff;
    #pragma unroll
    for (int n = 0; n < 4; ++n) rdB[n] = 8192 + (wc*64 + n*16 + lo)*32 + roff;

    f32x4 acc[8][4];
    #pragma unroll
    for (int m = 0; m < 8; ++m)
        #pragma unroll
        for (int n = 0; n < 4; ++n) acc[m][n] = (f32x4)(0.f);

    #pragma unroll
    for (int t0 = 0; t0 < 2; ++t0) {
        #pragma unroll
        for (int j = 0; j < 4; ++j) gl_lds16(aS[j] + t0*32, dA + t0*G1_SLOT + j*2048);
        #pragma unroll
        for (int j = 0; j < 2; ++j) gl_lds16(bS[j] + t0*32, dB + t0*G1_SLOT + j*2048);
    }
    VMC(6);
    BAR();

    const int NK = (FF/2)/32;   // 56
    int cur = 0, nxt = 2;
    for (int t = 0; t < NK; ++t) {
        const ushort* Lb = L + cur*G1_SLOT;
        const bool pf = (t + 2 < NK);
        s16x8 a[8], b[4];
        #pragma unroll
        for (int n = 0; n < 4; ++n) b[n] = *(const s16x8*)(Lb + rdB[n]);
        #pragma unroll
        for (int m = 0; m < 8; ++m) a[m] = *(const s16x8*)(Lb + rdA[m]);
        if (pf) {
            #pragma unroll
            for (int j = 0; j < 4; ++j)
                gl_lds16(aS[j] + (t+2)*32, dA + nxt*G1_SLOT + j*2048);
            gl_lds16(bS[0] + (t+2)*32, dB + nxt*G1_SLOT);
            gl_lds16(bS[1] + (t+2)*32, dB + nxt*G1_SLOT + 2048);
        }
        BAR();
        __builtin_amdgcn_s_setprio(1);
        #pragma unroll
        for (int m = 0; m < 8; ++m)
            #pragma unroll
            for (int n = 0; n < 4; ++n)
                acc[m][n] = __builtin_amdgcn_mfma_f32_16x16x32_bf16(a[m], b[n], acc[m][n], 0, 0, 0);
        __builtin_amdgcn_s_setprio(0);
        if (t < NK-2) { VMC(6); } else { VMC(0); }
        BAR();
        cur = (cur == 2) ? 0 : cur + 1;
        nxt = (nxt == 2) ? 0 : nxt + 1;
    }

    // epilogue: plain bf16 stores to res[z][prow][d] — no atomics, deterministic
    ushort* rz = res + (size_t)blockIdx.z * CAP * DIM;
    #pragma unroll
    for (int m = 0; m < 8; ++m)
        #pragma unroll
        for (int j = 0; j < 4; ++j) {
            int prow = rowStart + wr*128 + m*16 + hi*4 + j;
            #pragma unroll
            for (int n = 0; n < 4; ++n) {
                int d = dc + wc*64 + n*16 + lo;
                rz[(size_t)prow*DIM + d] = f2b(acc[m][n][j]);
            }
        }
}

// ---------------- combine: out[t] = wA*(res0+res1)[pA] + wB*(res0+res1)[pB] --
__global__ __launch_bounds__(256)
void k_combine(const ushort* __restrict__ res, const int* __restrict__ tokPos,
               const float* __restrict__ topw, float* __restrict__ out)
{
    int i = blockIdx.x*256 + threadIdx.x;    // 8-elem group
    int t = i >> 7;                           // D/8 = 128 groups per token
    int g = i & 127;
    int pA = tokPos[2*t], pB = tokPos[2*t+1];
    float wA = topw[2*t], wB = topw[2*t+1];
    const ushort* res1 = res + (size_t)CAP * DIM;
    uint4 a0 = *(const uint4*)(res  + (size_t)pA*DIM + g*8);
    uint4 a1 = *(const uint4*)(res1 + (size_t)pA*DIM + g*8);
    uint4 b0 = *(const uint4*)(res  + (size_t)pB*DIM + g*8);
    uint4 b1 = *(const uint4*)(res1 + (size_t)pB*DIM + g*8);
    float4 o0, o1;
    o0.x = wA*(blo(a0.x)+blo(a1.x)) + wB*(blo(b0.x)+blo(b1.x));
    o0.y = wA*(bhi(a0.x)+bhi(a1.x)) + wB*(bhi(b0.x)+bhi(b1.x));
    o0.z = wA*(blo(a0.y)+blo(a1.y)) + wB*(blo(b0.y)+blo(b1.y));
    o0.w = wA*(bhi(a0.y)+bhi(a1.y)) + wB*(bhi(b0.y)+bhi(b1.y));
    o1.x = wA*(blo(a0.z)+blo(a1.z)) + wB*(blo(b0.z)+blo(b1.z));
    o1.y = wA*(bhi(a0.z)+bhi(a1.z)) + wB*(bhi(b0.z)+bhi(b1.z));
    o1.z = wA*(blo(a0.w)+blo(a1.w)) + wB*(blo(b0.w)+blo(b1.w));
    o1.w = wA*(bhi(a0.w)+bhi(a1.w)) + wB*(bhi(b0.w)+bhi(b1.w));
    float4* dst = (float4*)(out + (size_t)t*DIM + g*8);
    dst[0] = o0; dst[1] = o1;
}

// ---------------- launch ----------------
extern "C" void kernel_launch(void* const* d_in, const int* in_sizes, int n_in,
                              void* d_out, int out_size, void* d_ws, size_t ws_size,
                              hipStream_t stream)
{
    const float* x  = (const float*)d_in[0];
    const float* gw = (const float*)d_in[1];
    const float* w1 = (const float*)d_in[2];
    const float* w3 = (const float*)d_in[3];
    const float* w2 = (const float*)d_in[4];
    float* out = (float*)d_out;
    char* ws = (char*)d_ws;
    if (ws_size < WS_NEED) return;   // fail loudly

    int*    counts = (int*)ws;
    int*    cursor = counts + 8;
    int*    offs   = counts + 16;
    int*    topi   = (int*)  (ws + OFF_TOPI);
    float*  topw   = (float*)(ws + OFF_TOPW);
    int*    rowTok = (int*)  (ws + OFF_ROWTOK);
    int*    tokPos = (int*)  (ws + OFF_TOKPOS);
    ushort* w1b    = (ushort*)(ws + OFF_W1B);
    ushort* w3b    = (ushort*)(ws + OFF_W3B);
    ushort* w2b    = (ushort*)(ws + OFF_W2B);
    ushort* res    = (ushort*)(ws + OFF_RES);
    ushort* h      = (ushort*)(ws + OFF_H);
    ushort* xb     = (ushort*)d_out;          // xb lives in d_out until combine

    hipMemsetAsync(ws, 0, 256, stream);   // counts + cursor

    k_route  <<<T_TOK/4, 256, 0, stream>>>(x, gw, topi, topw, counts, xb);
    k_scan   <<<1, 256, 0, stream>>>(counts, offs, rowTok);
    k_scatter<<<T_TOK/256, 256, 0, stream>>>(topi, offs, cursor, rowTok, tokPos);
    k_cvt2   <<<2*CVT_HALF, 256, 0, stream>>>(w1, w3, w1b, w3b);
    k_gemm1  <<<dim3(56, CAP/256), 256, 0, stream>>>(xb, w1b, w3b, offs, rowTok, h);
    k_cvt    <<<(NE*DIM*FF/8)/256, 256, 0, stream>>>(w2, w2b);   // overlays w1b
    k_gemm2  <<<dim3(8, CAP/256, 2), 256, 0, stream>>>(h, w2b, offs, res);
    k_combine<<<(T_TOK*DIM/8)/256, 256, 0, stream>>>(res, tokPos, topw, out);
}